// Round 6
// baseline (480.583 us; speedup 1.0000x reference)
//
#include <hip/hip_runtime.h>

#define T_SEQ   2048
#define NHEADS  16
#define DHEAD   64
#define DMODEL  1024
#define ALPHA_C 1.4142135f
#define EPS_C   1e-5f

typedef __attribute__((ext_vector_type(8))) short bf16x8;
typedef __attribute__((ext_vector_type(4))) short bf16x4;
typedef __attribute__((ext_vector_type(4))) float floatx4;

__device__ __forceinline__ float bf2f(unsigned short u) {
  union { unsigned int i; float f; } v;
  v.i = ((unsigned int)u) << 16;
  return v.f;
}
__device__ __forceinline__ unsigned short f2bf(float f) {
  union { float f; unsigned int i; } v;
  v.f = f;
  unsigned int u = v.i;
  u += 0x7FFF + ((u >> 16) & 1);   // RNE (finite data only)
  return (unsigned short)(u >> 16);
}

__device__ __forceinline__ void gload_lds16(const void* g, void* l) {
  __builtin_amdgcn_global_load_lds(
      (const __attribute__((address_space(1))) void*)g,
      (__attribute__((address_space(3))) void*)l, 16, 0, 0);
}

// ---------------------------------------------------------------------------
// f32 -> bf16 bulk convert (8 elems/thread, n % 2048 == 0)
// ---------------------------------------------------------------------------
__global__ void f32_to_bf16(const float* __restrict__ in,
                            unsigned short* __restrict__ out)
{
  int i = (blockIdx.x * 256 + threadIdx.x) * 8;
  floatx4 a = *(const floatx4*)(in + i);
  floatx4 b = *(const floatx4*)(in + i + 4);
  bf16x8 o;
  #pragma unroll
  for (int u = 0; u < 4; u++) {
    o[u]     = (short)f2bf(a[u]);
    o[4 + u] = (short)f2bf(b[u]);
  }
  *(bf16x8*)(out + i) = o;
}

// ---------------------------------------------------------------------------
// Generic GEMM (m97 structure): C[M,N] = A[M,K] @ W[N,K]^T (+ bias), bf16,
// fp32 accum. BM=128, BK=32, BN templated. global_load_lds width=16.
// ---------------------------------------------------------------------------
template<int BN>
__global__ __launch_bounds__(256) void gemm_lds(
    const unsigned short* __restrict__ A,
    const unsigned short* __restrict__ W,
    unsigned short* __restrict__ C,
    const float* __restrict__ bias,
    int M, int N, int K, int lda)
{
  constexpr int WN = BN / 2;
  constexpr int NJ = WN / 16;
  __shared__ unsigned short As[128 * 32];
  __shared__ unsigned short Bs[BN * 32];

  const int tid  = threadIdx.x;
  const int lane = tid & 63;
  const int wave = tid >> 6;
  const int wm = (wave >> 1) * 64;
  const int wn = (wave & 1) * WN;
  const int mBase = blockIdx.y * 128;
  const int nBase = blockIdx.x * BN;

  const int sRow = lane >> 2;
  const int sCol = (lane & 3) * 8;

  floatx4 acc[4][NJ];
  #pragma unroll
  for (int i = 0; i < 4; i++)
    #pragma unroll
    for (int j = 0; j < NJ; j++) acc[i][j] = (floatx4){0.f, 0.f, 0.f, 0.f};

  const int mrow = lane & 15;
  const int kq   = (lane >> 4) * 8;

  for (int kb = 0; kb < K; kb += 32) {
    __syncthreads();
    #pragma unroll
    for (int j = 0; j < 2; j++) {
      int r = wave * 32 + j * 16 + sRow;
      gload_lds16(A + (size_t)(mBase + r) * lda + kb + sCol,
                  &As[wave * 1024 + j * 512 + lane * 8]);
    }
    if constexpr (BN == 128) {
      #pragma unroll
      for (int j = 0; j < 2; j++) {
        int r = wave * 32 + j * 16 + sRow;
        gload_lds16(W + (size_t)(nBase + r) * K + kb + sCol,
                    &Bs[wave * 1024 + j * 512 + lane * 8]);
      }
    } else {
      int r = wave * 16 + sRow;
      gload_lds16(W + (size_t)(nBase + r) * K + kb + sCol,
                  &Bs[wave * 512 + lane * 8]);
    }
    __syncthreads();

    bf16x8 af[4], bfr[NJ];
    #pragma unroll
    for (int i = 0; i < 4; i++)
      af[i] = *(const bf16x8*)&As[(wm + i * 16 + mrow) * 32 + kq];
    #pragma unroll
    for (int j = 0; j < NJ; j++)
      bfr[j] = *(const bf16x8*)&Bs[(wn + j * 16 + mrow) * 32 + kq];
    #pragma unroll
    for (int i = 0; i < 4; i++)
      #pragma unroll
      for (int j = 0; j < NJ; j++)
        acc[i][j] = __builtin_amdgcn_mfma_f32_16x16x32_bf16(af[i], bfr[j], acc[i][j], 0, 0, 0);
  }

  const int col0 = lane & 15;
  const int row0 = (lane >> 4) * 4;
  #pragma unroll
  for (int j = 0; j < NJ; j++) {
    const int col = nBase + wn + j * 16 + col0;
    const float badd = bias ? bias[col] : 0.f;
    #pragma unroll
    for (int i = 0; i < 4; i++) {
      #pragma unroll
      for (int r = 0; r < 4; r++) {
        const int row = mBase + wm + i * 16 + row0 + r;
        C[(size_t)row * N + col] = f2bf(acc[i][j][r] + badd);
      }
    }
  }
}

// ---------------------------------------------------------------------------
// qkv GEMM with fused RoPE + head-split. C-cols [nBase+wn, +64) lie in ONE
// head of ONE section (q/k/v); thread's 4 j-cols are {c, c+16, c+32, c+48} =
// exactly the RoPE pairs (i,i+32) for i = c, c+16. Writes q/k (roped) and v
// directly in [B*H, T, 64] layout. M=4096, N=3072, K=1024.
// ---------------------------------------------------------------------------
__global__ __launch_bounds__(256) void gemm_qkv_rope(
    const unsigned short* __restrict__ A,
    const unsigned short* __restrict__ W,
    unsigned short* __restrict__ Qd,
    unsigned short* __restrict__ Kd,
    unsigned short* __restrict__ Vd)
{
  constexpr int K = 1024;
  __shared__ unsigned short As[128 * 32];
  __shared__ unsigned short Bs[128 * 32];

  const int tid  = threadIdx.x;
  const int lane = tid & 63;
  const int wave = tid >> 6;
  const int wm = (wave >> 1) * 64;
  const int wn = (wave & 1) * 64;
  const int mBase = blockIdx.y * 128;
  const int nBase = blockIdx.x * 128;

  const int sRow = lane >> 2;
  const int sCol = (lane & 3) * 8;

  floatx4 acc[4][4];
  #pragma unroll
  for (int i = 0; i < 4; i++)
    #pragma unroll
    for (int j = 0; j < 4; j++) acc[i][j] = (floatx4){0.f, 0.f, 0.f, 0.f};

  const int mrow = lane & 15;
  const int kq   = (lane >> 4) * 8;

  for (int kb = 0; kb < K; kb += 32) {
    __syncthreads();
    #pragma unroll
    for (int j = 0; j < 2; j++) {
      int r = wave * 32 + j * 16 + sRow;
      gload_lds16(A + (size_t)(mBase + r) * K + kb + sCol,
                  &As[wave * 1024 + j * 512 + lane * 8]);
      gload_lds16(W + (size_t)(nBase + r) * K + kb + sCol,
                  &Bs[wave * 1024 + j * 512 + lane * 8]);
    }
    __syncthreads();

    bf16x8 af[4], bfr[4];
    #pragma unroll
    for (int i = 0; i < 4; i++) {
      af[i]  = *(const bf16x8*)&As[(wm + i * 16 + mrow) * 32 + kq];
      bfr[i] = *(const bf16x8*)&Bs[(wn + i * 16 + mrow) * 32 + kq];
    }
    #pragma unroll
    for (int i = 0; i < 4; i++)
      #pragma unroll
      for (int j = 0; j < 4; j++)
        acc[i][j] = __builtin_amdgcn_mfma_f32_16x16x32_bf16(af[i], bfr[j], acc[i][j], 0, 0, 0);
  }

  const int col0 = lane & 15;
  const int row0 = (lane >> 4) * 4;
  const int colBase = nBase + wn;          // multiple of 64, block/wave-uniform
  const int sect = colBase >> 10;          // 0=q, 1=k, 2=v
  const int h    = (colBase & 1023) >> 6;  // head index
  unsigned short* dst = (sect == 0) ? Qd : (sect == 1) ? Kd : Vd;

  if (sect < 2) {
    const float fr0 = powf(10000.f, -(float)col0 * (1.f / 32.f));
    const float fr1 = powf(10000.f, -(float)(col0 + 16) * (1.f / 32.f));
    #pragma unroll
    for (int it = 0; it < 4; it++) {
      #pragma unroll
      for (int r = 0; r < 4; r++) {
        const int row = mBase + wm + it * 16 + row0 + r;
        const int b = row >> 11, t = row & 2047;
        size_t ob = ((size_t)((b * NHEADS + h) * T_SEQ + t)) * DHEAD;
        float s0, c0, s1, c1;
        sincosf((float)t * fr0, &s0, &c0);
        sincosf((float)t * fr1, &s1, &c1);
        float x1a = acc[it][0][r], x2a = acc[it][2][r];
        float x1b = acc[it][1][r], x2b = acc[it][3][r];
        dst[ob + col0]      = f2bf(x1a * c0 - x2a * s0);
        dst[ob + col0 + 32] = f2bf(x2a * c0 + x1a * s0);
        dst[ob + col0 + 16] = f2bf(x1b * c1 - x2b * s1);
        dst[ob + col0 + 48] = f2bf(x2b * c1 + x1b * s1);
      }
    }
  } else {
    #pragma unroll
    for (int it = 0; it < 4; it++)
      #pragma unroll
      for (int j = 0; j < 4; j++)
        #pragma unroll
        for (int r = 0; r < 4; r++) {
          const int row = mBase + wm + it * 16 + row0 + r;
          const int b = row >> 11, t = row & 2047;
          dst[((size_t)((b * NHEADS + h) * T_SEQ + t)) * DHEAD + j * 16 + col0] =
              f2bf(acc[it][j][r]);
        }
  }
}

// ---------------------------------------------------------------------------
// W1 GEMM with fused SwiGLU: per block, y-tile (W1 rows n..n+128) and
// gate-tile (W1 rows 4096+n..) share the A-tile; epilogue writes
// ys = y * g * sigmoid(g), compact [4096, 4096]. M=4096, K=1024.
// ---------------------------------------------------------------------------
__global__ __launch_bounds__(256) void gemm_w1_swiglu(
    const unsigned short* __restrict__ A,
    const unsigned short* __restrict__ W1,
    unsigned short* __restrict__ ys)
{
  constexpr int K = 1024;
  __shared__ unsigned short As[128 * 32];
  __shared__ unsigned short Bs[256 * 32];   // [0:128) y rows, [128:256) gate

  const int tid  = threadIdx.x;
  const int lane = tid & 63;
  const int wave = tid >> 6;
  const int wm = (wave >> 1) * 64;
  const int wn = (wave & 1) * 64;
  const int mBase = blockIdx.y * 128;
  const int nBase = blockIdx.x * 128;

  const int sRow = lane >> 2;
  const int sCol = (lane & 3) * 8;

  floatx4 accY[4][4], accG[4][4];
  #pragma unroll
  for (int i = 0; i < 4; i++)
    #pragma unroll
    for (int j = 0; j < 4; j++) {
      accY[i][j] = (floatx4){0.f, 0.f, 0.f, 0.f};
      accG[i][j] = (floatx4){0.f, 0.f, 0.f, 0.f};
    }

  const int mrow = lane & 15;
  const int kq   = (lane >> 4) * 8;

  for (int kb = 0; kb < K; kb += 32) {
    __syncthreads();
    #pragma unroll
    for (int j = 0; j < 2; j++) {
      int r = wave * 32 + j * 16 + sRow;
      gload_lds16(A + (size_t)(mBase + r) * K + kb + sCol,
                  &As[wave * 1024 + j * 512 + lane * 8]);
      gload_lds16(W1 + (size_t)(nBase + r) * K + kb + sCol,
                  &Bs[wave * 1024 + j * 512 + lane * 8]);
      gload_lds16(W1 + (size_t)(4096 + nBase + r) * K + kb + sCol,
                  &Bs[4096 + wave * 1024 + j * 512 + lane * 8]);
    }
    __syncthreads();

    bf16x8 af[4], by[4], bg[4];
    #pragma unroll
    for (int i = 0; i < 4; i++) {
      af[i] = *(const bf16x8*)&As[(wm + i * 16 + mrow) * 32 + kq];
      by[i] = *(const bf16x8*)&Bs[(wn + i * 16 + mrow) * 32 + kq];
      bg[i] = *(const bf16x8*)&Bs[4096 + (wn + i * 16 + mrow) * 32 + kq];
    }
    #pragma unroll
    for (int i = 0; i < 4; i++)
      #pragma unroll
      for (int j = 0; j < 4; j++) {
        accY[i][j] = __builtin_amdgcn_mfma_f32_16x16x32_bf16(af[i], by[j], accY[i][j], 0, 0, 0);
        accG[i][j] = __builtin_amdgcn_mfma_f32_16x16x32_bf16(af[i], bg[j], accG[i][j], 0, 0, 0);
      }
  }

  const int col0 = lane & 15;
  const int row0 = (lane >> 4) * 4;
  #pragma unroll
  for (int j = 0; j < 4; j++) {
    const int col = nBase + wn + j * 16 + col0;
    #pragma unroll
    for (int i = 0; i < 4; i++) {
      #pragma unroll
      for (int r = 0; r < 4; r++) {
        const int row = mBase + wm + i * 16 + row0 + r;
        float y = accY[i][j][r], g = accG[i][j][r];
        float sig = 1.f / (1.f + __expf(-g));
        ys[(size_t)row * 4096 + col] = f2bf(y * g * sig);
      }
    }
  }
}

// ---------------------------------------------------------------------------
// MFMA banded attention (round-5 kernel, unchanged).
// ---------------------------------------------------------------------------
__global__ __launch_bounds__(256) void attn_mfma(
    const unsigned short* __restrict__ Qg,
    const unsigned short* __restrict__ Kg,
    const unsigned short* __restrict__ Vg,
    unsigned short* __restrict__ Og)
{
  __shared__ unsigned short KV[23040];   // K tile [320][72]; then V^T [64][328]
  __shared__ unsigned short Qs[64 * 72];
  __shared__ unsigned short Ps[4 * 16 * 328];

  const int tid  = threadIdx.x;
  const int lane = tid & 63;
  const int wave = tid >> 6;
  const int c    = lane & 15;
  const int quad = lane >> 4;
  const int blk  = blockIdx.x;
  const int bh   = blk >> 5;
  const int qBase = (blk & 31) * 64;
  const size_t hbase = (size_t)bh * T_SEQ * DHEAD;

  for (int e = tid; e < 320 * 8; e += 256) {
    int row = e >> 3, ch = e & 7;
    int kg = qBase - 127 + row;
    int kgc = min(max(kg, 0), T_SEQ - 1);
    *(bf16x8*)&KV[row * 72 + ch * 8] =
        *(const bf16x8*)(Kg + hbase + (size_t)kgc * DHEAD + ch * 8);
  }
  for (int e = tid; e < 64 * 8; e += 256) {
    int row = e >> 3, ch = e & 7;
    *(bf16x8*)&Qs[row * 72 + ch * 8] =
        *(const bf16x8*)(Qg + hbase + (size_t)(qBase + row) * DHEAD + ch * 8);
  }
  __syncthreads();

  bf16x8 aq[2];
  #pragma unroll
  for (int hh = 0; hh < 2; hh++)
    aq[hh] = *(const bf16x8*)&Qs[(wave * 16 + c) * 72 + hh * 32 + quad * 8];

  floatx4 s[20];
  #pragma unroll
  for (int kt = 0; kt < 20; kt++) {
    bf16x8 b0 = *(const bf16x8*)&KV[(kt * 16 + c) * 72 + quad * 8];
    bf16x8 b1 = *(const bf16x8*)&KV[(kt * 16 + c) * 72 + 32 + quad * 8];
    floatx4 t = (floatx4){0.f, 0.f, 0.f, 0.f};
    t = __builtin_amdgcn_mfma_f32_16x16x32_bf16(aq[0], b0, t, 0, 0, 0);
    t = __builtin_amdgcn_mfma_f32_16x16x32_bf16(aq[1], b1, t, 0, 0, 0);
    s[kt] = t;
  }
  __syncthreads();

  for (int ch = wave; ch < 5; ch += 4) {
    int koff = ch * 64 + lane;
    int kg = qBase - 127 + koff;
    int kgc = min(max(kg, 0), T_SEQ - 1);
    const unsigned short* vrow = Vg + hbase + (size_t)kgc * DHEAD;
    #pragma unroll
    for (int dg = 0; dg < 8; dg++) {
      bf16x8 v8 = *(const bf16x8*)(vrow + dg * 8);
      #pragma unroll
      for (int j = 0; j < 8; j++)
        KV[(dg * 8 + j) * 328 + koff] = (unsigned short)v8[j];
    }
  }

  const int kLoMin = max(0, 127 - qBase);
  const int kHiMax = min(319, 2047 + 127 - qBase);
  float mx[4] = {-3e38f, -3e38f, -3e38f, -3e38f};
  #pragma unroll
  for (int kt = 0; kt < 20; kt++) {
    const int koff = kt * 16 + c;
    #pragma unroll
    for (int reg = 0; reg < 4; reg++) {
      const int qrow = wave * 16 + quad * 4 + reg;
      const int d = koff - qrow;
      bool ok = (d >= 0) && (d <= 255) && (koff >= kLoMin) && (koff <= kHiMax);
      float val = ok ? s[kt][reg] * 0.125f : -3e38f;
      s[kt][reg] = val;
      mx[reg] = fmaxf(mx[reg], val);
    }
  }
  #pragma unroll
  for (int reg = 0; reg < 4; reg++)
    #pragma unroll
    for (int m = 1; m <= 8; m <<= 1)
      mx[reg] = fmaxf(mx[reg], __shfl_xor(mx[reg], m));

  float ls[4] = {0.f, 0.f, 0.f, 0.f};
  #pragma unroll
  for (int kt = 0; kt < 20; kt++) {
    const int koff = kt * 16 + c;
    #pragma unroll
    for (int reg = 0; reg < 4; reg++) {
      float p = __expf(s[kt][reg] - mx[reg]);
      ls[reg] += p;
      Ps[wave * 5248 + (quad * 4 + reg) * 328 + koff] = f2bf(p);
    }
  }
  float inv[4];
  #pragma unroll
  for (int reg = 0; reg < 4; reg++) {
    #pragma unroll
    for (int m = 1; m <= 8; m <<= 1) ls[reg] += __shfl_xor(ls[reg], m);
    inv[reg] = 1.f / ls[reg];
  }
  __syncthreads();

  floatx4 oacc[4];
  #pragma unroll
  for (int nt = 0; nt < 4; nt++) oacc[nt] = (floatx4){0.f, 0.f, 0.f, 0.f};
  #pragma unroll
  for (int kt2 = 0; kt2 < 10; kt2++) {
    bf16x8 a = *(const bf16x8*)&Ps[wave * 5248 + c * 328 + kt2 * 32 + quad * 8];
    #pragma unroll
    for (int nt = 0; nt < 4; nt++) {
      bf16x8 bb = *(const bf16x8*)&KV[(nt * 16 + c) * 328 + kt2 * 32 + quad * 8];
      oacc[nt] = __builtin_amdgcn_mfma_f32_16x16x32_bf16(a, bb, oacc[nt], 0, 0, 0);
    }
  }

  const int b = bh >> 4, h = bh & 15;
  #pragma unroll
  for (int nt = 0; nt < 4; nt++) {
    #pragma unroll
    for (int reg = 0; reg < 4; reg++) {
      const int qg = qBase + wave * 16 + quad * 4 + reg;
      Og[((size_t)(b * T_SEQ + qg)) * DMODEL + h * DHEAD + nt * 16 + c] =
          f2bf(oacc[nt][reg] * inv[reg]);
    }
  }
}

// ---------------------------------------------------------------------------
// out = rmsnorm(a + ALPHA*xres, g). a bf16; xres f32/bf16; g f32; out f32/bf16.
// ---------------------------------------------------------------------------
template<bool XRES_F32, bool OUT_F32>
__global__ __launch_bounds__(256) void resid_rmsnorm(
    const unsigned short* __restrict__ a,
    const void* __restrict__ xresp,
    const float* __restrict__ g,
    void* __restrict__ outp)
{
  __shared__ float red[4];
  const int row = blockIdx.x;
  const int tid = threadIdx.x;
  const size_t base = (size_t)row * DMODEL;
  float s[4];
  float ss = 0.f;
  #pragma unroll
  for (int r = 0; r < 4; r++) {
    int c = r * 256 + tid;
    float xr = XRES_F32 ? ((const float*)xresp)[base + c]
                        : bf2f(((const unsigned short*)xresp)[base + c]);
    float vv = bf2f(a[base + c]) + ALPHA_C * xr;
    s[r] = vv;
    ss += vv * vv;
  }
  #pragma unroll
  for (int m = 1; m <= 32; m <<= 1) ss += __shfl_xor(ss, m);
  if ((tid & 63) == 0) red[tid >> 6] = ss;
  __syncthreads();
  float ms = (red[0] + red[1] + red[2] + red[3]) * (1.f / DMODEL);
  float scl = rsqrtf(ms + EPS_C);
  #pragma unroll
  for (int r = 0; r < 4; r++) {
    int c = r * 256 + tid;
    float o = s[r] * scl * g[c];
    if (OUT_F32) ((float*)outp)[base + c] = o;
    else ((unsigned short*)outp)[base + c] = f2bf(o);
  }
}

// ---------------------------------------------------------------------------
// Workspace plan (bf16 elems), peak 41,943,040 = 80 MiB:
//   [0,        16.78M)  bf16 weights (persistent)
//   [16.78M,   20.97M)  P1: xb -> tmp -> tmp2     (serial reuse)
//   [20.97M,   25.17M)  x2
//   [25.17M,   37.75M)  q,k,v  -> ys [4096,4096] after attn (16.78M)
//   [37.75M,   41.94M)  o (dead after step 4; ys tail overlaps afterwards)
// ---------------------------------------------------------------------------
extern "C" void kernel_launch(void* const* d_in, const int* in_sizes, int n_in,
                              void* d_out, int out_size, void* d_ws, size_t ws_size,
                              hipStream_t stream) {
  (void)in_sizes; (void)n_in; (void)out_size; (void)ws_size;
  const float* x    = (const float*)d_in[0];
  const float* Wqkv = (const float*)d_in[1];
  const float* Wout = (const float*)d_in[2];
  const float* bout = (const float*)d_in[3];
  const float* W1   = (const float*)d_in[4];
  const float* W2   = (const float*)d_in[5];
  const float* g1   = (const float*)d_in[6];
  const float* g2   = (const float*)d_in[7];
  float* out = (float*)d_out;

  unsigned short* ws    = (unsigned short*)d_ws;
  unsigned short* Wqkvb = ws;                    //  3,145,728
  unsigned short* Woutb = ws + 3145728;          //  1,048,576
  unsigned short* W1b   = ws + 4194304;          //  8,388,608
  unsigned short* W2b   = ws + 12582912;         //  4,194,304
  unsigned short* P1    = ws + 16777216;         //  4,194,304 (xb/tmp/tmp2)
  unsigned short* x2    = ws + 20971520;         //  4,194,304
  unsigned short* q     = ws + 25165824;         //  4,194,304
  unsigned short* k     = ws + 29360128;
  unsigned short* v     = ws + 33554432;
  unsigned short* o     = ws + 37748736;         //  4,194,304
  unsigned short* ys    = ws + 25165824;         // 16,777,216 (q/k/v dead; o
                                                 //  dead before ys tail used)

  // 0. f32 -> bf16 conversions (weights + x)
  f32_to_bf16<<<1536, 256, 0, stream>>>(Wqkv, Wqkvb);
  f32_to_bf16<<< 512, 256, 0, stream>>>(Wout, Woutb);
  f32_to_bf16<<<4096, 256, 0, stream>>>(W1, W1b);
  f32_to_bf16<<<2048, 256, 0, stream>>>(W2, W2b);
  f32_to_bf16<<<2048, 256, 0, stream>>>(x, P1);
  // 1. qkv GEMM + fused RoPE/split -> q,k,v [B*H,T,64]
  gemm_qkv_rope<<<dim3(24, 32), 256, 0, stream>>>(P1, Wqkvb, q, k, v);
  // 2. MFMA banded attention -> o [B,T,1024]
  attn_mfma<<<32 * (T_SEQ / 64), 256, 0, stream>>>(q, k, v, o);
  // 3. a = o @ Wout^T + bout -> P1
  gemm_lds<64><<<dim3(16, 32), 256, 0, stream>>>(o, Woutb, P1, bout, 4096, 1024, 1024, 1024);
  // 4. x2 = rmsnorm(a + ALPHA*x, g1)
  resid_rmsnorm<true, false><<<4096, 256, 0, stream>>>(P1, x, g1, x2);
  // 5. W1 GEMM + fused SwiGLU -> ys [4096,4096]
  gemm_w1_swiglu<<<dim3(32, 32), 256, 0, stream>>>(x2, W1b, ys);
  // 6. y2 = ys @ W2^T -> P1
  gemm_lds<64><<<dim3(16, 32), 256, 0, stream>>>(ys, W2b, P1, nullptr, 4096, 1024, 4096, 4096);
  // 7. out = rmsnorm(y2 + ALPHA*x2, g2)
  resid_rmsnorm<false, true><<<4096, 256, 0, stream>>>(P1, x2, g2, out);
}

// Round 8
// 424.236 us; speedup vs baseline: 1.1328x; 1.1328x over previous
//
#include <hip/hip_runtime.h>

#define T_SEQ   2048
#define NHEADS  16
#define DHEAD   64
#define DMODEL  1024
#define ALPHA_C 1.4142135f
#define EPS_C   1e-5f

typedef __attribute__((ext_vector_type(8))) short bf16x8;
typedef __attribute__((ext_vector_type(4))) short bf16x4;
typedef __attribute__((ext_vector_type(4))) float floatx4;

__device__ __forceinline__ float bf2f(unsigned short u) {
  union { unsigned int i; float f; } v;
  v.i = ((unsigned int)u) << 16;
  return v.f;
}
__device__ __forceinline__ unsigned short f2bf(float f) {
  union { float f; unsigned int i; } v;
  v.f = f;
  unsigned int u = v.i;
  u += 0x7FFF + ((u >> 16) & 1);   // RNE (finite data only)
  return (unsigned short)(u >> 16);
}

__device__ __forceinline__ void gload_lds16(const void* g, void* l) {
  __builtin_amdgcn_global_load_lds(
      (const __attribute__((address_space(1))) void*)g,
      (__attribute__((address_space(3))) void*)l, 16, 0, 0);
}

// ---------------------------------------------------------------------------
// f32 -> bf16 bulk convert (8 elems/thread, n % 2048 == 0)
// ---------------------------------------------------------------------------
__global__ void f32_to_bf16(const float* __restrict__ in,
                            unsigned short* __restrict__ out)
{
  int i = (blockIdx.x * 256 + threadIdx.x) * 8;
  floatx4 a = *(const floatx4*)(in + i);
  floatx4 b = *(const floatx4*)(in + i + 4);
  bf16x8 o;
  #pragma unroll
  for (int u = 0; u < 4; u++) {
    o[u]     = (short)f2bf(a[u]);
    o[4 + u] = (short)f2bf(b[u]);
  }
  *(bf16x8*)(out + i) = o;
}

// ---------------------------------------------------------------------------
// Generic GEMM (m97 structure): C[M,N] = A[M,K] @ W[N,K]^T (+ bias), bf16,
// fp32 accum. BM=128, BK=32, BN templated. global_load_lds width=16.
// ---------------------------------------------------------------------------
template<int BN>
__global__ __launch_bounds__(256) void gemm_lds(
    const unsigned short* __restrict__ A,
    const unsigned short* __restrict__ W,
    unsigned short* __restrict__ C,
    const float* __restrict__ bias,
    int M, int N, int K, int lda)
{
  constexpr int WN = BN / 2;
  constexpr int NJ = WN / 16;
  __shared__ unsigned short As[128 * 32];
  __shared__ unsigned short Bs[BN * 32];

  const int tid  = threadIdx.x;
  const int lane = tid & 63;
  const int wave = tid >> 6;
  const int wm = (wave >> 1) * 64;
  const int wn = (wave & 1) * WN;
  const int mBase = blockIdx.y * 128;
  const int nBase = blockIdx.x * BN;

  const int sRow = lane >> 2;
  const int sCol = (lane & 3) * 8;

  floatx4 acc[4][NJ];
  #pragma unroll
  for (int i = 0; i < 4; i++)
    #pragma unroll
    for (int j = 0; j < NJ; j++) acc[i][j] = (floatx4){0.f, 0.f, 0.f, 0.f};

  const int mrow = lane & 15;
  const int kq   = (lane >> 4) * 8;

  for (int kb = 0; kb < K; kb += 32) {
    __syncthreads();
    #pragma unroll
    for (int j = 0; j < 2; j++) {
      int r = wave * 32 + j * 16 + sRow;
      gload_lds16(A + (size_t)(mBase + r) * lda + kb + sCol,
                  &As[wave * 1024 + j * 512 + lane * 8]);
    }
    if constexpr (BN == 128) {
      #pragma unroll
      for (int j = 0; j < 2; j++) {
        int r = wave * 32 + j * 16 + sRow;
        gload_lds16(W + (size_t)(nBase + r) * K + kb + sCol,
                    &Bs[wave * 1024 + j * 512 + lane * 8]);
      }
    } else {
      int r = wave * 16 + sRow;
      gload_lds16(W + (size_t)(nBase + r) * K + kb + sCol,
                  &Bs[wave * 512 + lane * 8]);
    }
    __syncthreads();

    bf16x8 af[4], bfr[NJ];
    #pragma unroll
    for (int i = 0; i < 4; i++)
      af[i] = *(const bf16x8*)&As[(wm + i * 16 + mrow) * 32 + kq];
    #pragma unroll
    for (int j = 0; j < NJ; j++)
      bfr[j] = *(const bf16x8*)&Bs[(wn + j * 16 + mrow) * 32 + kq];
    #pragma unroll
    for (int i = 0; i < 4; i++)
      #pragma unroll
      for (int j = 0; j < NJ; j++)
        acc[i][j] = __builtin_amdgcn_mfma_f32_16x16x32_bf16(af[i], bfr[j], acc[i][j], 0, 0, 0);
  }

  const int col0 = lane & 15;
  const int row0 = (lane >> 4) * 4;
  #pragma unroll
  for (int j = 0; j < NJ; j++) {
    const int col = nBase + wn + j * 16 + col0;
    const float badd = bias ? bias[col] : 0.f;
    #pragma unroll
    for (int i = 0; i < 4; i++) {
      #pragma unroll
      for (int r = 0; r < 4; r++) {
        const int row = mBase + wm + i * 16 + row0 + r;
        C[(size_t)row * N + col] = f2bf(acc[i][j][r] + badd);
      }
    }
  }
}

// ---------------------------------------------------------------------------
// qkv GEMM with fused RoPE + head-split (round-6 kernel, unchanged).
// ---------------------------------------------------------------------------
__global__ __launch_bounds__(256) void gemm_qkv_rope(
    const unsigned short* __restrict__ A,
    const unsigned short* __restrict__ W,
    unsigned short* __restrict__ Qd,
    unsigned short* __restrict__ Kd,
    unsigned short* __restrict__ Vd)
{
  constexpr int K = 1024;
  __shared__ unsigned short As[128 * 32];
  __shared__ unsigned short Bs[128 * 32];

  const int tid  = threadIdx.x;
  const int lane = tid & 63;
  const int wave = tid >> 6;
  const int wm = (wave >> 1) * 64;
  const int wn = (wave & 1) * 64;
  const int mBase = blockIdx.y * 128;
  const int nBase = blockIdx.x * 128;

  const int sRow = lane >> 2;
  const int sCol = (lane & 3) * 8;

  floatx4 acc[4][4];
  #pragma unroll
  for (int i = 0; i < 4; i++)
    #pragma unroll
    for (int j = 0; j < 4; j++) acc[i][j] = (floatx4){0.f, 0.f, 0.f, 0.f};

  const int mrow = lane & 15;
  const int kq   = (lane >> 4) * 8;

  for (int kb = 0; kb < K; kb += 32) {
    __syncthreads();
    #pragma unroll
    for (int j = 0; j < 2; j++) {
      int r = wave * 32 + j * 16 + sRow;
      gload_lds16(A + (size_t)(mBase + r) * K + kb + sCol,
                  &As[wave * 1024 + j * 512 + lane * 8]);
      gload_lds16(W + (size_t)(nBase + r) * K + kb + sCol,
                  &Bs[wave * 1024 + j * 512 + lane * 8]);
    }
    __syncthreads();

    bf16x8 af[4], bfr[4];
    #pragma unroll
    for (int i = 0; i < 4; i++) {
      af[i]  = *(const bf16x8*)&As[(wm + i * 16 + mrow) * 32 + kq];
      bfr[i] = *(const bf16x8*)&Bs[(wn + i * 16 + mrow) * 32 + kq];
    }
    #pragma unroll
    for (int i = 0; i < 4; i++)
      #pragma unroll
      for (int j = 0; j < 4; j++)
        acc[i][j] = __builtin_amdgcn_mfma_f32_16x16x32_bf16(af[i], bfr[j], acc[i][j], 0, 0, 0);
  }

  const int col0 = lane & 15;
  const int row0 = (lane >> 4) * 4;
  const int colBase = nBase + wn;          // multiple of 64, block/wave-uniform
  const int sect = colBase >> 10;          // 0=q, 1=k, 2=v
  const int h    = (colBase & 1023) >> 6;  // head index
  unsigned short* dst = (sect == 0) ? Qd : (sect == 1) ? Kd : Vd;

  if (sect < 2) {
    const float fr0 = powf(10000.f, -(float)col0 * (1.f / 32.f));
    const float fr1 = powf(10000.f, -(float)(col0 + 16) * (1.f / 32.f));
    #pragma unroll
    for (int it = 0; it < 4; it++) {
      #pragma unroll
      for (int r = 0; r < 4; r++) {
        const int row = mBase + wm + it * 16 + row0 + r;
        const int b = row >> 11, t = row & 2047;
        size_t ob = ((size_t)((b * NHEADS + h) * T_SEQ + t)) * DHEAD;
        float s0, c0, s1, c1;
        sincosf((float)t * fr0, &s0, &c0);
        sincosf((float)t * fr1, &s1, &c1);
        float x1a = acc[it][0][r], x2a = acc[it][2][r];
        float x1b = acc[it][1][r], x2b = acc[it][3][r];
        dst[ob + col0]      = f2bf(x1a * c0 - x2a * s0);
        dst[ob + col0 + 32] = f2bf(x2a * c0 + x1a * s0);
        dst[ob + col0 + 16] = f2bf(x1b * c1 - x2b * s1);
        dst[ob + col0 + 48] = f2bf(x2b * c1 + x1b * s1);
      }
    }
  } else {
    #pragma unroll
    for (int it = 0; it < 4; it++)
      #pragma unroll
      for (int j = 0; j < 4; j++)
        #pragma unroll
        for (int r = 0; r < 4; r++) {
          const int row = mBase + wm + it * 16 + row0 + r;
          const int b = row >> 11, t = row & 2047;
          dst[((size_t)((b * NHEADS + h) * T_SEQ + t)) * DHEAD + j * 16 + col0] =
              f2bf(acc[it][j][r]);
        }
  }
}

// ---------------------------------------------------------------------------
// W1 GEMM with fused SwiGLU, 128x64 tile. FIXED staging: each wave issues
// TWO B-loads covering 32 rows, 4 waves -> all 128 B rows (64 y + 64 gate).
// Wave w: half = w>>1 (0=y,1=gate), rows (w&1)*32 + j*16 + sRow (j=0,1).
// ---------------------------------------------------------------------------
__global__ __launch_bounds__(256) void gemm_w1_swiglu(
    const unsigned short* __restrict__ A,
    const unsigned short* __restrict__ W1,
    unsigned short* __restrict__ ys)
{
  constexpr int K = 1024;
  __shared__ unsigned short As[128 * 32];
  __shared__ unsigned short Bs[128 * 32];   // [0:2048) y rows, [2048:4096) gate

  const int tid  = threadIdx.x;
  const int lane = tid & 63;
  const int wave = tid >> 6;
  const int wm = (wave >> 1) * 64;
  const int wn = (wave & 1) * 32;
  const int mBase = blockIdx.y * 128;
  const int nBase = blockIdx.x * 64;

  const int sRow = lane >> 2;
  const int sCol = (lane & 3) * 8;

  floatx4 accY[4][2], accG[4][2];
  #pragma unroll
  for (int i = 0; i < 4; i++)
    #pragma unroll
    for (int j = 0; j < 2; j++) {
      accY[i][j] = (floatx4){0.f, 0.f, 0.f, 0.f};
      accG[i][j] = (floatx4){0.f, 0.f, 0.f, 0.f};
    }

  const int mrow = lane & 15;
  const int kq   = (lane >> 4) * 8;
  const int half = wave >> 1;               // 0 = y, 1 = gate

  for (int kb = 0; kb < K; kb += 32) {
    __syncthreads();
    #pragma unroll
    for (int j = 0; j < 2; j++) {
      int r = wave * 32 + j * 16 + sRow;
      gload_lds16(A + (size_t)(mBase + r) * K + kb + sCol,
                  &As[wave * 1024 + j * 512 + lane * 8]);
    }
    #pragma unroll
    for (int j = 0; j < 2; j++) {
      int r = (wave & 1) * 32 + j * 16 + sRow;       // 0..63 within half
      gload_lds16(W1 + (size_t)(half * 4096 + nBase + r) * K + kb + sCol,
                  &Bs[half * 2048 + (wave & 1) * 1024 + j * 512 + lane * 8]);
    }
    __syncthreads();

    bf16x8 af[4], by[2], bg[2];
    #pragma unroll
    for (int i = 0; i < 4; i++)
      af[i] = *(const bf16x8*)&As[(wm + i * 16 + mrow) * 32 + kq];
    #pragma unroll
    for (int j = 0; j < 2; j++) {
      by[j] = *(const bf16x8*)&Bs[(wn + j * 16 + mrow) * 32 + kq];
      bg[j] = *(const bf16x8*)&Bs[2048 + (wn + j * 16 + mrow) * 32 + kq];
    }
    #pragma unroll
    for (int i = 0; i < 4; i++)
      #pragma unroll
      for (int j = 0; j < 2; j++) {
        accY[i][j] = __builtin_amdgcn_mfma_f32_16x16x32_bf16(af[i], by[j], accY[i][j], 0, 0, 0);
        accG[i][j] = __builtin_amdgcn_mfma_f32_16x16x32_bf16(af[i], bg[j], accG[i][j], 0, 0, 0);
      }
  }

  const int col0 = lane & 15;
  const int row0 = (lane >> 4) * 4;
  #pragma unroll
  for (int j = 0; j < 2; j++) {
    const int col = nBase + wn + j * 16 + col0;
    #pragma unroll
    for (int i = 0; i < 4; i++) {
      #pragma unroll
      for (int r = 0; r < 4; r++) {
        const int row = mBase + wm + i * 16 + row0 + r;
        float y = accY[i][j][r], g = accG[i][j][r];
        float sig = 1.f / (1.f + __expf(-g));
        ys[(size_t)row * 4096 + col] = f2bf(y * g * sig);
      }
    }
  }
}

// ---------------------------------------------------------------------------
// MFMA banded attention (round-5 kernel, unchanged).
// ---------------------------------------------------------------------------
__global__ __launch_bounds__(256) void attn_mfma(
    const unsigned short* __restrict__ Qg,
    const unsigned short* __restrict__ Kg,
    const unsigned short* __restrict__ Vg,
    unsigned short* __restrict__ Og)
{
  __shared__ unsigned short KV[23040];   // K tile [320][72]; then V^T [64][328]
  __shared__ unsigned short Qs[64 * 72];
  __shared__ unsigned short Ps[4 * 16 * 328];

  const int tid  = threadIdx.x;
  const int lane = tid & 63;
  const int wave = tid >> 6;
  const int c    = lane & 15;
  const int quad = lane >> 4;
  const int blk  = blockIdx.x;
  const int bh   = blk >> 5;
  const int qBase = (blk & 31) * 64;
  const size_t hbase = (size_t)bh * T_SEQ * DHEAD;

  for (int e = tid; e < 320 * 8; e += 256) {
    int row = e >> 3, ch = e & 7;
    int kg = qBase - 127 + row;
    int kgc = min(max(kg, 0), T_SEQ - 1);
    *(bf16x8*)&KV[row * 72 + ch * 8] =
        *(const bf16x8*)(Kg + hbase + (size_t)kgc * DHEAD + ch * 8);
  }
  for (int e = tid; e < 64 * 8; e += 256) {
    int row = e >> 3, ch = e & 7;
    *(bf16x8*)&Qs[row * 72 + ch * 8] =
        *(const bf16x8*)(Qg + hbase + (size_t)(qBase + row) * DHEAD + ch * 8);
  }
  __syncthreads();

  bf16x8 aq[2];
  #pragma unroll
  for (int hh = 0; hh < 2; hh++)
    aq[hh] = *(const bf16x8*)&Qs[(wave * 16 + c) * 72 + hh * 32 + quad * 8];

  floatx4 s[20];
  #pragma unroll
  for (int kt = 0; kt < 20; kt++) {
    bf16x8 b0 = *(const bf16x8*)&KV[(kt * 16 + c) * 72 + quad * 8];
    bf16x8 b1 = *(const bf16x8*)&KV[(kt * 16 + c) * 72 + 32 + quad * 8];
    floatx4 t = (floatx4){0.f, 0.f, 0.f, 0.f};
    t = __builtin_amdgcn_mfma_f32_16x16x32_bf16(aq[0], b0, t, 0, 0, 0);
    t = __builtin_amdgcn_mfma_f32_16x16x32_bf16(aq[1], b1, t, 0, 0, 0);
    s[kt] = t;
  }
  __syncthreads();

  for (int ch = wave; ch < 5; ch += 4) {
    int koff = ch * 64 + lane;
    int kg = qBase - 127 + koff;
    int kgc = min(max(kg, 0), T_SEQ - 1);
    const unsigned short* vrow = Vg + hbase + (size_t)kgc * DHEAD;
    #pragma unroll
    for (int dg = 0; dg < 8; dg++) {
      bf16x8 v8 = *(const bf16x8*)(vrow + dg * 8);
      #pragma unroll
      for (int j = 0; j < 8; j++)
        KV[(dg * 8 + j) * 328 + koff] = (unsigned short)v8[j];
    }
  }

  const int kLoMin = max(0, 127 - qBase);
  const int kHiMax = min(319, 2047 + 127 - qBase);
  float mx[4] = {-3e38f, -3e38f, -3e38f, -3e38f};
  #pragma unroll
  for (int kt = 0; kt < 20; kt++) {
    const int koff = kt * 16 + c;
    #pragma unroll
    for (int reg = 0; reg < 4; reg++) {
      const int qrow = wave * 16 + quad * 4 + reg;
      const int d = koff - qrow;
      bool ok = (d >= 0) && (d <= 255) && (koff >= kLoMin) && (koff <= kHiMax);
      float val = ok ? s[kt][reg] * 0.125f : -3e38f;
      s[kt][reg] = val;
      mx[reg] = fmaxf(mx[reg], val);
    }
  }
  #pragma unroll
  for (int reg = 0; reg < 4; reg++)
    #pragma unroll
    for (int m = 1; m <= 8; m <<= 1)
      mx[reg] = fmaxf(mx[reg], __shfl_xor(mx[reg], m));

  float ls[4] = {0.f, 0.f, 0.f, 0.f};
  #pragma unroll
  for (int kt = 0; kt < 20; kt++) {
    const int koff = kt * 16 + c;
    #pragma unroll
    for (int reg = 0; reg < 4; reg++) {
      float p = __expf(s[kt][reg] - mx[reg]);
      ls[reg] += p;
      Ps[wave * 5248 + (quad * 4 + reg) * 328 + koff] = f2bf(p);
    }
  }
  float inv[4];
  #pragma unroll
  for (int reg = 0; reg < 4; reg++) {
    #pragma unroll
    for (int m = 1; m <= 8; m <<= 1) ls[reg] += __shfl_xor(ls[reg], m);
    inv[reg] = 1.f / ls[reg];
  }
  __syncthreads();

  floatx4 oacc[4];
  #pragma unroll
  for (int nt = 0; nt < 4; nt++) oacc[nt] = (floatx4){0.f, 0.f, 0.f, 0.f};
  #pragma unroll
  for (int kt2 = 0; kt2 < 10; kt2++) {
    bf16x8 a = *(const bf16x8*)&Ps[wave * 5248 + c * 328 + kt2 * 32 + quad * 8];
    #pragma unroll
    for (int nt = 0; nt < 4; nt++) {
      bf16x8 bb = *(const bf16x8*)&KV[(nt * 16 + c) * 328 + kt2 * 32 + quad * 8];
      oacc[nt] = __builtin_amdgcn_mfma_f32_16x16x32_bf16(a, bb, oacc[nt], 0, 0, 0);
    }
  }

  const int b = bh >> 4, h = bh & 15;
  #pragma unroll
  for (int nt = 0; nt < 4; nt++) {
    #pragma unroll
    for (int reg = 0; reg < 4; reg++) {
      const int qg = qBase + wave * 16 + quad * 4 + reg;
      Og[((size_t)(b * T_SEQ + qg)) * DMODEL + h * DHEAD + nt * 16 + c] =
          f2bf(oacc[nt][reg] * inv[reg]);
    }
  }
}

// ---------------------------------------------------------------------------
// out = rmsnorm(a + ALPHA*xres, g). a bf16; xres f32/bf16; g f32; out f32/bf16.
// ---------------------------------------------------------------------------
template<bool XRES_F32, bool OUT_F32>
__global__ __launch_bounds__(256) void resid_rmsnorm(
    const unsigned short* __restrict__ a,
    const void* __restrict__ xresp,
    const float* __restrict__ g,
    void* __restrict__ outp)
{
  __shared__ float red[4];
  const int row = blockIdx.x;
  const int tid = threadIdx.x;
  const size_t base = (size_t)row * DMODEL;
  float s[4];
  float ss = 0.f;
  #pragma unroll
  for (int r = 0; r < 4; r++) {
    int c = r * 256 + tid;
    float xr = XRES_F32 ? ((const float*)xresp)[base + c]
                        : bf2f(((const unsigned short*)xresp)[base + c]);
    float vv = bf2f(a[base + c]) + ALPHA_C * xr;
    s[r] = vv;
    ss += vv * vv;
  }
  #pragma unroll
  for (int m = 1; m <= 32; m <<= 1) ss += __shfl_xor(ss, m);
  if ((tid & 63) == 0) red[tid >> 6] = ss;
  __syncthreads();
  float ms = (red[0] + red[1] + red[2] + red[3]) * (1.f / DMODEL);
  float scl = rsqrtf(ms + EPS_C);
  #pragma unroll
  for (int r = 0; r < 4; r++) {
    int c = r * 256 + tid;
    float o = s[r] * scl * g[c];
    if (OUT_F32) ((float*)outp)[base + c] = o;
    else ((unsigned short*)outp)[base + c] = f2bf(o);
  }
}

// ---------------------------------------------------------------------------
// Workspace plan (bf16 elems), peak 41,943,040 = 80 MiB.
// ---------------------------------------------------------------------------
extern "C" void kernel_launch(void* const* d_in, const int* in_sizes, int n_in,
                              void* d_out, int out_size, void* d_ws, size_t ws_size,
                              hipStream_t stream) {
  (void)in_sizes; (void)n_in; (void)out_size; (void)ws_size;
  const float* x    = (const float*)d_in[0];
  const float* Wqkv = (const float*)d_in[1];
  const float* Wout = (const float*)d_in[2];
  const float* bout = (const float*)d_in[3];
  const float* W1   = (const float*)d_in[4];
  const float* W2   = (const float*)d_in[5];
  const float* g1   = (const float*)d_in[6];
  const float* g2   = (const float*)d_in[7];
  float* out = (float*)d_out;

  unsigned short* ws    = (unsigned short*)d_ws;
  unsigned short* Wqkvb = ws;                    //  3,145,728
  unsigned short* Woutb = ws + 3145728;          //  1,048,576
  unsigned short* W1b   = ws + 4194304;          //  8,388,608
  unsigned short* W2b   = ws + 12582912;         //  4,194,304
  unsigned short* P1    = ws + 16777216;         //  4,194,304 (xb/tmp/tmp2)
  unsigned short* x2    = ws + 20971520;         //  4,194,304
  unsigned short* q     = ws + 25165824;         //  4,194,304
  unsigned short* k     = ws + 29360128;
  unsigned short* v     = ws + 33554432;
  unsigned short* o     = ws + 37748736;         //  4,194,304
  unsigned short* ys    = ws + 25165824;         // 16,777,216 (q/k/v dead)

  // 0. f32 -> bf16 conversions (weights + x)
  f32_to_bf16<<<1536, 256, 0, stream>>>(Wqkv, Wqkvb);
  f32_to_bf16<<< 512, 256, 0, stream>>>(Wout, Woutb);
  f32_to_bf16<<<4096, 256, 0, stream>>>(W1, W1b);
  f32_to_bf16<<<2048, 256, 0, stream>>>(W2, W2b);
  f32_to_bf16<<<2048, 256, 0, stream>>>(x, P1);
  // 1. qkv GEMM + fused RoPE/split -> q,k,v [B*H,T,64]
  gemm_qkv_rope<<<dim3(24, 32), 256, 0, stream>>>(P1, Wqkvb, q, k, v);
  // 2. MFMA banded attention -> o [B,T,1024]
  attn_mfma<<<32 * (T_SEQ / 64), 256, 0, stream>>>(q, k, v, o);
  // 3. a = o @ Wout^T + bout -> P1
  gemm_lds<64><<<dim3(16, 32), 256, 0, stream>>>(o, Woutb, P1, bout, 4096, 1024, 1024, 1024);
  // 4. x2 = rmsnorm(a + ALPHA*x, g1)
  resid_rmsnorm<true, false><<<4096, 256, 0, stream>>>(P1, x, g1, x2);
  // 5. W1 GEMM + fused SwiGLU -> ys [4096,4096]  (128x64 tile, staging fixed)
  gemm_w1_swiglu<<<dim3(64, 32), 256, 0, stream>>>(x2, W1b, ys);
  // 6. y2 = ys @ W2^T -> P1
  gemm_lds<64><<<dim3(16, 32), 256, 0, stream>>>(ys, W2b, P1, nullptr, 4096, 1024, 4096, 4096);
  // 7. out = rmsnorm(y2 + ALPHA*x2, g2)
  resid_rmsnorm<false, true><<<4096, 256, 0, stream>>>(P1, x2, g2, out);
}

// Round 9
// 399.471 us; speedup vs baseline: 1.2030x; 1.0620x over previous
//
#include <hip/hip_runtime.h>

#define T_SEQ   2048
#define NHEADS  16
#define DHEAD   64
#define DMODEL  1024
#define ALPHA_C 1.4142135f
#define EPS_C   1e-5f

typedef __attribute__((ext_vector_type(8))) short bf16x8;
typedef __attribute__((ext_vector_type(4))) short bf16x4;
typedef __attribute__((ext_vector_type(4))) float floatx4;

__device__ __forceinline__ float bf2f(unsigned short u) {
  union { unsigned int i; float f; } v;
  v.i = ((unsigned int)u) << 16;
  return v.f;
}
__device__ __forceinline__ unsigned short f2bf(float f) {
  union { float f; unsigned int i; } v;
  v.f = f;
  unsigned int u = v.i;
  u += 0x7FFF + ((u >> 16) & 1);   // RNE (finite data only)
  return (unsigned short)(u >> 16);
}

__device__ __forceinline__ void gload_lds16(const void* g, void* l) {
  __builtin_amdgcn_global_load_lds(
      (const __attribute__((address_space(1))) void*)g,
      (__attribute__((address_space(3))) void*)l, 16, 0, 0);
}

// ---------------------------------------------------------------------------
// Merged f32->bf16 convert of all 5 inputs into ws[0 : 20971520).
// Region boundaries are multiples of 2048 (one block's span) -> wave-uniform.
// ---------------------------------------------------------------------------
__global__ void convert_all(const float* __restrict__ Wqkv,
                            const float* __restrict__ Wout,
                            const float* __restrict__ W1,
                            const float* __restrict__ W2,
                            const float* __restrict__ x,
                            unsigned short* __restrict__ ws)
{
  size_t i = ((size_t)blockIdx.x * 256 + threadIdx.x) * 8;
  const float* src;
  size_t off;
  if      (i <  3145728) { src = Wqkv; off = i; }
  else if (i <  4194304) { src = Wout; off = i -  3145728; }
  else if (i < 12582912) { src = W1;   off = i -  4194304; }
  else if (i < 16777216) { src = W2;   off = i - 12582912; }
  else                   { src = x;    off = i - 16777216; }
  floatx4 a = *(const floatx4*)(src + off);
  floatx4 b = *(const floatx4*)(src + off + 4);
  bf16x8 o;
  #pragma unroll
  for (int u = 0; u < 4; u++) {
    o[u]     = (short)f2bf(a[u]);
    o[4 + u] = (short)f2bf(b[u]);
  }
  *(bf16x8*)(ws + i) = o;
}

// ---------------------------------------------------------------------------
// RoPE LUT: cos/sin of t * 10000^(-i/32) for t in [0,2048), i in [0,32).
// ---------------------------------------------------------------------------
__global__ void build_rope_lut(float* __restrict__ cosT,
                               float* __restrict__ sinT)
{
  int gid = blockIdx.x * 256 + threadIdx.x;   // 65536 entries
  int t = gid >> 5, i = gid & 31;
  float fr = powf(10000.f, -(float)i * (1.f / 32.f));
  float sn, cs;
  sincosf((float)t * fr, &sn, &cs);
  cosT[gid] = cs;
  sinT[gid] = sn;
}

// ---------------------------------------------------------------------------
// Generic GEMM (m97 structure): C = A @ W^T (+ bias), bf16, fp32 accum.
// BM=128, BK=32, BN templated. global_load_lds width=16.
// ---------------------------------------------------------------------------
template<int BN>
__global__ __launch_bounds__(256) void gemm_lds(
    const unsigned short* __restrict__ A,
    const unsigned short* __restrict__ W,
    unsigned short* __restrict__ C,
    const float* __restrict__ bias,
    int M, int N, int K, int lda)
{
  constexpr int WN = BN / 2;
  constexpr int NJ = WN / 16;
  __shared__ unsigned short As[128 * 32];
  __shared__ unsigned short Bs[BN * 32];

  const int tid  = threadIdx.x;
  const int lane = tid & 63;
  const int wave = tid >> 6;
  const int wm = (wave >> 1) * 64;
  const int wn = (wave & 1) * WN;
  const int mBase = blockIdx.y * 128;
  const int nBase = blockIdx.x * BN;

  const int sRow = lane >> 2;
  const int sCol = (lane & 3) * 8;

  floatx4 acc[4][NJ];
  #pragma unroll
  for (int i = 0; i < 4; i++)
    #pragma unroll
    for (int j = 0; j < NJ; j++) acc[i][j] = (floatx4){0.f, 0.f, 0.f, 0.f};

  const int mrow = lane & 15;
  const int kq   = (lane >> 4) * 8;

  for (int kb = 0; kb < K; kb += 32) {
    __syncthreads();
    #pragma unroll
    for (int j = 0; j < 2; j++) {
      int r = wave * 32 + j * 16 + sRow;
      gload_lds16(A + (size_t)(mBase + r) * lda + kb + sCol,
                  &As[wave * 1024 + j * 512 + lane * 8]);
    }
    if constexpr (BN == 128) {
      #pragma unroll
      for (int j = 0; j < 2; j++) {
        int r = wave * 32 + j * 16 + sRow;
        gload_lds16(W + (size_t)(nBase + r) * K + kb + sCol,
                    &Bs[wave * 1024 + j * 512 + lane * 8]);
      }
    } else {
      int r = wave * 16 + sRow;
      gload_lds16(W + (size_t)(nBase + r) * K + kb + sCol,
                  &Bs[wave * 512 + lane * 8]);
    }
    __syncthreads();

    bf16x8 af[4], bfr[NJ];
    #pragma unroll
    for (int i = 0; i < 4; i++)
      af[i] = *(const bf16x8*)&As[(wm + i * 16 + mrow) * 32 + kq];
    #pragma unroll
    for (int j = 0; j < NJ; j++)
      bfr[j] = *(const bf16x8*)&Bs[(wn + j * 16 + mrow) * 32 + kq];
    #pragma unroll
    for (int i = 0; i < 4; i++)
      #pragma unroll
      for (int j = 0; j < NJ; j++)
        acc[i][j] = __builtin_amdgcn_mfma_f32_16x16x32_bf16(af[i], bfr[j], acc[i][j], 0, 0, 0);
  }

  const int col0 = lane & 15;
  const int row0 = (lane >> 4) * 4;
  #pragma unroll
  for (int j = 0; j < NJ; j++) {
    const int col = nBase + wn + j * 16 + col0;
    const float badd = bias ? bias[col] : 0.f;
    #pragma unroll
    for (int i = 0; i < 4; i++) {
      #pragma unroll
      for (int r = 0; r < 4; r++) {
        const int row = mBase + wm + i * 16 + row0 + r;
        C[(size_t)row * N + col] = f2bf(acc[i][j][r] + badd);
      }
    }
  }
}

// ---------------------------------------------------------------------------
// Split-K W2 GEMM: y2 = ys[4096,4096] @ W2[1024,4096]^T, K split in 2 halves
// (blockIdx.z). f32 partials Cp[z][4096][1024]; reduced in final rmsnorm.
// BM=128, BN=64, BK=32.
// ---------------------------------------------------------------------------
__global__ __launch_bounds__(256) void gemm_w2_splitk(
    const unsigned short* __restrict__ A,
    const unsigned short* __restrict__ W,
    float* __restrict__ Cp)
{
  __shared__ unsigned short As[128 * 32];
  __shared__ unsigned short Bs[64 * 32];

  const int tid  = threadIdx.x;
  const int lane = tid & 63;
  const int wave = tid >> 6;
  const int wm = (wave >> 1) * 64;
  const int wn = (wave & 1) * 32;
  const int mBase = blockIdx.y * 128;
  const int nBase = blockIdx.x * 64;
  const int kOff  = blockIdx.z * 2048;

  const int sRow = lane >> 2;
  const int sCol = (lane & 3) * 8;

  floatx4 acc[4][2];
  #pragma unroll
  for (int i = 0; i < 4; i++)
    #pragma unroll
    for (int j = 0; j < 2; j++) acc[i][j] = (floatx4){0.f, 0.f, 0.f, 0.f};

  const int mrow = lane & 15;
  const int kq   = (lane >> 4) * 8;

  for (int kb = 0; kb < 2048; kb += 32) {
    __syncthreads();
    #pragma unroll
    for (int j = 0; j < 2; j++) {
      int r = wave * 32 + j * 16 + sRow;
      gload_lds16(A + (size_t)(mBase + r) * 4096 + kOff + kb + sCol,
                  &As[wave * 1024 + j * 512 + lane * 8]);
    }
    {
      int r = wave * 16 + sRow;
      gload_lds16(W + (size_t)(nBase + r) * 4096 + kOff + kb + sCol,
                  &Bs[wave * 512 + lane * 8]);
    }
    __syncthreads();

    bf16x8 af[4], bfr[2];
    #pragma unroll
    for (int i = 0; i < 4; i++)
      af[i] = *(const bf16x8*)&As[(wm + i * 16 + mrow) * 32 + kq];
    #pragma unroll
    for (int j = 0; j < 2; j++)
      bfr[j] = *(const bf16x8*)&Bs[(wn + j * 16 + mrow) * 32 + kq];
    #pragma unroll
    for (int i = 0; i < 4; i++)
      #pragma unroll
      for (int j = 0; j < 2; j++)
        acc[i][j] = __builtin_amdgcn_mfma_f32_16x16x32_bf16(af[i], bfr[j], acc[i][j], 0, 0, 0);
  }

  const int col0 = lane & 15;
  const int row0 = (lane >> 4) * 4;
  float* dst = Cp + (size_t)blockIdx.z * 4096 * 1024;
  #pragma unroll
  for (int j = 0; j < 2; j++) {
    const int col = nBase + wn + j * 16 + col0;
    #pragma unroll
    for (int i = 0; i < 4; i++)
      #pragma unroll
      for (int r = 0; r < 4; r++) {
        const int row = mBase + wm + i * 16 + row0 + r;
        dst[(size_t)row * 1024 + col] = acc[i][j][r];
      }
  }
}

// ---------------------------------------------------------------------------
// qkv GEMM with fused RoPE + head-split; trig from LUT.
// ---------------------------------------------------------------------------
__global__ __launch_bounds__(256) void gemm_qkv_rope(
    const unsigned short* __restrict__ A,
    const unsigned short* __restrict__ W,
    const float* __restrict__ cosT,
    const float* __restrict__ sinT,
    unsigned short* __restrict__ Qd,
    unsigned short* __restrict__ Kd,
    unsigned short* __restrict__ Vd)
{
  constexpr int K = 1024;
  __shared__ unsigned short As[128 * 32];
  __shared__ unsigned short Bs[128 * 32];

  const int tid  = threadIdx.x;
  const int lane = tid & 63;
  const int wave = tid >> 6;
  const int wm = (wave >> 1) * 64;
  const int wn = (wave & 1) * 64;
  const int mBase = blockIdx.y * 128;
  const int nBase = blockIdx.x * 128;

  const int sRow = lane >> 2;
  const int sCol = (lane & 3) * 8;

  floatx4 acc[4][4];
  #pragma unroll
  for (int i = 0; i < 4; i++)
    #pragma unroll
    for (int j = 0; j < 4; j++) acc[i][j] = (floatx4){0.f, 0.f, 0.f, 0.f};

  const int mrow = lane & 15;
  const int kq   = (lane >> 4) * 8;

  for (int kb = 0; kb < K; kb += 32) {
    __syncthreads();
    #pragma unroll
    for (int j = 0; j < 2; j++) {
      int r = wave * 32 + j * 16 + sRow;
      gload_lds16(A + (size_t)(mBase + r) * K + kb + sCol,
                  &As[wave * 1024 + j * 512 + lane * 8]);
      gload_lds16(W + (size_t)(nBase + r) * K + kb + sCol,
                  &Bs[wave * 1024 + j * 512 + lane * 8]);
    }
    __syncthreads();

    bf16x8 af[4], bfr[4];
    #pragma unroll
    for (int i = 0; i < 4; i++) {
      af[i]  = *(const bf16x8*)&As[(wm + i * 16 + mrow) * 32 + kq];
      bfr[i] = *(const bf16x8*)&Bs[(wn + i * 16 + mrow) * 32 + kq];
    }
    #pragma unroll
    for (int i = 0; i < 4; i++)
      #pragma unroll
      for (int j = 0; j < 4; j++)
        acc[i][j] = __builtin_amdgcn_mfma_f32_16x16x32_bf16(af[i], bfr[j], acc[i][j], 0, 0, 0);
  }

  const int col0 = lane & 15;
  const int row0 = (lane >> 4) * 4;
  const int colBase = nBase + wn;          // multiple of 64, wave-uniform
  const int sect = colBase >> 10;          // 0=q, 1=k, 2=v
  const int h    = (colBase & 1023) >> 6;  // head index
  unsigned short* dst = (sect == 0) ? Qd : (sect == 1) ? Kd : Vd;

  if (sect < 2) {
    #pragma unroll
    for (int it = 0; it < 4; it++) {
      #pragma unroll
      for (int r = 0; r < 4; r++) {
        const int row = mBase + wm + it * 16 + row0 + r;
        const int b = row >> 11, t = row & 2047;
        size_t ob = ((size_t)((b * NHEADS + h) * T_SEQ + t)) * DHEAD;
        const int tb = t * 32;
        float c0 = cosT[tb + col0],      s0 = sinT[tb + col0];
        float c1 = cosT[tb + col0 + 16], s1 = sinT[tb + col0 + 16];
        float x1a = acc[it][0][r], x2a = acc[it][2][r];
        float x1b = acc[it][1][r], x2b = acc[it][3][r];
        dst[ob + col0]      = f2bf(x1a * c0 - x2a * s0);
        dst[ob + col0 + 32] = f2bf(x2a * c0 + x1a * s0);
        dst[ob + col0 + 16] = f2bf(x1b * c1 - x2b * s1);
        dst[ob + col0 + 48] = f2bf(x2b * c1 + x1b * s1);
      }
    }
  } else {
    #pragma unroll
    for (int it = 0; it < 4; it++)
      #pragma unroll
      for (int j = 0; j < 4; j++)
        #pragma unroll
        for (int r = 0; r < 4; r++) {
          const int row = mBase + wm + it * 16 + row0 + r;
          const int b = row >> 11, t = row & 2047;
          dst[((size_t)((b * NHEADS + h) * T_SEQ + t)) * DHEAD + j * 16 + col0] =
              f2bf(acc[it][j][r]);
        }
  }
}

// ---------------------------------------------------------------------------
// W1 GEMM with fused SwiGLU, 128x64 tile (round-8 kernel, unchanged).
// ---------------------------------------------------------------------------
__global__ __launch_bounds__(256) void gemm_w1_swiglu(
    const unsigned short* __restrict__ A,
    const unsigned short* __restrict__ W1,
    unsigned short* __restrict__ ys)
{
  constexpr int K = 1024;
  __shared__ unsigned short As[128 * 32];
  __shared__ unsigned short Bs[128 * 32];   // [0:2048) y rows, [2048:4096) gate

  const int tid  = threadIdx.x;
  const int lane = tid & 63;
  const int wave = tid >> 6;
  const int wm = (wave >> 1) * 64;
  const int wn = (wave & 1) * 32;
  const int mBase = blockIdx.y * 128;
  const int nBase = blockIdx.x * 64;

  const int sRow = lane >> 2;
  const int sCol = (lane & 3) * 8;

  floatx4 accY[4][2], accG[4][2];
  #pragma unroll
  for (int i = 0; i < 4; i++)
    #pragma unroll
    for (int j = 0; j < 2; j++) {
      accY[i][j] = (floatx4){0.f, 0.f, 0.f, 0.f};
      accG[i][j] = (floatx4){0.f, 0.f, 0.f, 0.f};
    }

  const int mrow = lane & 15;
  const int kq   = (lane >> 4) * 8;
  const int half = wave >> 1;               // 0 = y, 1 = gate

  for (int kb = 0; kb < K; kb += 32) {
    __syncthreads();
    #pragma unroll
    for (int j = 0; j < 2; j++) {
      int r = wave * 32 + j * 16 + sRow;
      gload_lds16(A + (size_t)(mBase + r) * K + kb + sCol,
                  &As[wave * 1024 + j * 512 + lane * 8]);
    }
    #pragma unroll
    for (int j = 0; j < 2; j++) {
      int r = (wave & 1) * 32 + j * 16 + sRow;       // 0..63 within half
      gload_lds16(W1 + (size_t)(half * 4096 + nBase + r) * K + kb + sCol,
                  &Bs[half * 2048 + (wave & 1) * 1024 + j * 512 + lane * 8]);
    }
    __syncthreads();

    bf16x8 af[4], by[2], bg[2];
    #pragma unroll
    for (int i = 0; i < 4; i++)
      af[i] = *(const bf16x8*)&As[(wm + i * 16 + mrow) * 32 + kq];
    #pragma unroll
    for (int j = 0; j < 2; j++) {
      by[j] = *(const bf16x8*)&Bs[(wn + j * 16 + mrow) * 32 + kq];
      bg[j] = *(const bf16x8*)&Bs[2048 + (wn + j * 16 + mrow) * 32 + kq];
    }
    #pragma unroll
    for (int i = 0; i < 4; i++)
      #pragma unroll
      for (int j = 0; j < 2; j++) {
        accY[i][j] = __builtin_amdgcn_mfma_f32_16x16x32_bf16(af[i], by[j], accY[i][j], 0, 0, 0);
        accG[i][j] = __builtin_amdgcn_mfma_f32_16x16x32_bf16(af[i], bg[j], accG[i][j], 0, 0, 0);
      }
  }

  const int col0 = lane & 15;
  const int row0 = (lane >> 4) * 4;
  #pragma unroll
  for (int j = 0; j < 2; j++) {
    const int col = nBase + wn + j * 16 + col0;
    #pragma unroll
    for (int i = 0; i < 4; i++) {
      #pragma unroll
      for (int r = 0; r < 4; r++) {
        const int row = mBase + wm + i * 16 + row0 + r;
        float y = accY[i][j][r], g = accG[i][j][r];
        float sig = 1.f / (1.f + __expf(-g));
        ys[(size_t)row * 4096 + col] = f2bf(y * g * sig);
      }
    }
  }
}

// ---------------------------------------------------------------------------
// MFMA banded attention (round-5 kernel, unchanged).
// ---------------------------------------------------------------------------
__global__ __launch_bounds__(256) void attn_mfma(
    const unsigned short* __restrict__ Qg,
    const unsigned short* __restrict__ Kg,
    const unsigned short* __restrict__ Vg,
    unsigned short* __restrict__ Og)
{
  __shared__ unsigned short KV[23040];   // K tile [320][72]; then V^T [64][328]
  __shared__ unsigned short Qs[64 * 72];
  __shared__ unsigned short Ps[4 * 16 * 328];

  const int tid  = threadIdx.x;
  const int lane = tid & 63;
  const int wave = tid >> 6;
  const int c    = lane & 15;
  const int quad = lane >> 4;
  const int blk  = blockIdx.x;
  const int bh   = blk >> 5;
  const int qBase = (blk & 31) * 64;
  const size_t hbase = (size_t)bh * T_SEQ * DHEAD;

  for (int e = tid; e < 320 * 8; e += 256) {
    int row = e >> 3, ch = e & 7;
    int kg = qBase - 127 + row;
    int kgc = min(max(kg, 0), T_SEQ - 1);
    *(bf16x8*)&KV[row * 72 + ch * 8] =
        *(const bf16x8*)(Kg + hbase + (size_t)kgc * DHEAD + ch * 8);
  }
  for (int e = tid; e < 64 * 8; e += 256) {
    int row = e >> 3, ch = e & 7;
    *(bf16x8*)&Qs[row * 72 + ch * 8] =
        *(const bf16x8*)(Qg + hbase + (size_t)(qBase + row) * DHEAD + ch * 8);
  }
  __syncthreads();

  bf16x8 aq[2];
  #pragma unroll
  for (int hh = 0; hh < 2; hh++)
    aq[hh] = *(const bf16x8*)&Qs[(wave * 16 + c) * 72 + hh * 32 + quad * 8];

  floatx4 s[20];
  #pragma unroll
  for (int kt = 0; kt < 20; kt++) {
    bf16x8 b0 = *(const bf16x8*)&KV[(kt * 16 + c) * 72 + quad * 8];
    bf16x8 b1 = *(const bf16x8*)&KV[(kt * 16 + c) * 72 + 32 + quad * 8];
    floatx4 t = (floatx4){0.f, 0.f, 0.f, 0.f};
    t = __builtin_amdgcn_mfma_f32_16x16x32_bf16(aq[0], b0, t, 0, 0, 0);
    t = __builtin_amdgcn_mfma_f32_16x16x32_bf16(aq[1], b1, t, 0, 0, 0);
    s[kt] = t;
  }
  __syncthreads();

  for (int ch = wave; ch < 5; ch += 4) {
    int koff = ch * 64 + lane;
    int kg = qBase - 127 + koff;
    int kgc = min(max(kg, 0), T_SEQ - 1);
    const unsigned short* vrow = Vg + hbase + (size_t)kgc * DHEAD;
    #pragma unroll
    for (int dg = 0; dg < 8; dg++) {
      bf16x8 v8 = *(const bf16x8*)(vrow + dg * 8);
      #pragma unroll
      for (int j = 0; j < 8; j++)
        KV[(dg * 8 + j) * 328 + koff] = (unsigned short)v8[j];
    }
  }

  const int kLoMin = max(0, 127 - qBase);
  const int kHiMax = min(319, 2047 + 127 - qBase);
  float mx[4] = {-3e38f, -3e38f, -3e38f, -3e38f};
  #pragma unroll
  for (int kt = 0; kt < 20; kt++) {
    const int koff = kt * 16 + c;
    #pragma unroll
    for (int reg = 0; reg < 4; reg++) {
      const int qrow = wave * 16 + quad * 4 + reg;
      const int d = koff - qrow;
      bool ok = (d >= 0) && (d <= 255) && (koff >= kLoMin) && (koff <= kHiMax);
      float val = ok ? s[kt][reg] * 0.125f : -3e38f;
      s[kt][reg] = val;
      mx[reg] = fmaxf(mx[reg], val);
    }
  }
  #pragma unroll
  for (int reg = 0; reg < 4; reg++)
    #pragma unroll
    for (int m = 1; m <= 8; m <<= 1)
      mx[reg] = fmaxf(mx[reg], __shfl_xor(mx[reg], m));

  float ls[4] = {0.f, 0.f, 0.f, 0.f};
  #pragma unroll
  for (int kt = 0; kt < 20; kt++) {
    const int koff = kt * 16 + c;
    #pragma unroll
    for (int reg = 0; reg < 4; reg++) {
      float p = __expf(s[kt][reg] - mx[reg]);
      ls[reg] += p;
      Ps[wave * 5248 + (quad * 4 + reg) * 328 + koff] = f2bf(p);
    }
  }
  float inv[4];
  #pragma unroll
  for (int reg = 0; reg < 4; reg++) {
    #pragma unroll
    for (int m = 1; m <= 8; m <<= 1) ls[reg] += __shfl_xor(ls[reg], m);
    inv[reg] = 1.f / ls[reg];
  }
  __syncthreads();

  floatx4 oacc[4];
  #pragma unroll
  for (int nt = 0; nt < 4; nt++) oacc[nt] = (floatx4){0.f, 0.f, 0.f, 0.f};
  #pragma unroll
  for (int kt2 = 0; kt2 < 10; kt2++) {
    bf16x8 a = *(const bf16x8*)&Ps[wave * 5248 + c * 328 + kt2 * 32 + quad * 8];
    #pragma unroll
    for (int nt = 0; nt < 4; nt++) {
      bf16x8 bb = *(const bf16x8*)&KV[(nt * 16 + c) * 328 + kt2 * 32 + quad * 8];
      oacc[nt] = __builtin_amdgcn_mfma_f32_16x16x32_bf16(a, bb, oacc[nt], 0, 0, 0);
    }
  }

  const int b = bh >> 4, h = bh & 15;
  #pragma unroll
  for (int nt = 0; nt < 4; nt++) {
    #pragma unroll
    for (int reg = 0; reg < 4; reg++) {
      const int qg = qBase + wave * 16 + quad * 4 + reg;
      Og[((size_t)(b * T_SEQ + qg)) * DMODEL + h * DHEAD + nt * 16 + c] =
          f2bf(oacc[nt][reg] * inv[reg]);
    }
  }
}

// ---------------------------------------------------------------------------
// x2 = rmsnorm(a + ALPHA*x, g1): a bf16, x f32, out bf16. Vectorized x4.
// ---------------------------------------------------------------------------
__global__ __launch_bounds__(256) void rmsnorm_mid(
    const unsigned short* __restrict__ a,
    const float* __restrict__ x,
    const float* __restrict__ g,
    unsigned short* __restrict__ out)
{
  __shared__ float red[4];
  const int row = blockIdx.x;
  const int tid = threadIdx.x;
  const size_t base = (size_t)row * DMODEL;
  const int c = tid * 4;
  bf16x4  av = *(const bf16x4*)(a + base + c);
  floatx4 xv = *(const floatx4*)(x + base + c);
  floatx4 gv = *(const floatx4*)(g + c);
  float s[4], ss = 0.f;
  #pragma unroll
  for (int j = 0; j < 4; j++) {
    s[j] = bf2f((unsigned short)av[j]) + ALPHA_C * xv[j];
    ss += s[j] * s[j];
  }
  #pragma unroll
  for (int m = 1; m <= 32; m <<= 1) ss += __shfl_xor(ss, m);
  if ((tid & 63) == 0) red[tid >> 6] = ss;
  __syncthreads();
  float ms = (red[0] + red[1] + red[2] + red[3]) * (1.f / DMODEL);
  float scl = rsqrtf(ms + EPS_C);
  bf16x4 ov;
  #pragma unroll
  for (int j = 0; j < 4; j++) ov[j] = (short)f2bf(s[j] * scl * gv[j]);
  *(bf16x4*)(out + base + c) = ov;
}

// ---------------------------------------------------------------------------
// out = rmsnorm((p0+p1) + ALPHA*x2, g2): p0/p1 f32 split-K partials,
// x2 bf16, out f32. Vectorized x4.
// ---------------------------------------------------------------------------
__global__ __launch_bounds__(256) void rmsnorm_final_sk(
    const float* __restrict__ p0,
    const float* __restrict__ p1,
    const unsigned short* __restrict__ x2,
    const float* __restrict__ g,
    float* __restrict__ out)
{
  __shared__ float red[4];
  const int row = blockIdx.x;
  const int tid = threadIdx.x;
  const size_t base = (size_t)row * DMODEL;
  const int c = tid * 4;
  floatx4 a0 = *(const floatx4*)(p0 + base + c);
  floatx4 a1 = *(const floatx4*)(p1 + base + c);
  bf16x4  xv = *(const bf16x4*)(x2 + base + c);
  floatx4 gv = *(const floatx4*)(g + c);
  float s[4], ss = 0.f;
  #pragma unroll
  for (int j = 0; j < 4; j++) {
    s[j] = (a0[j] + a1[j]) + ALPHA_C * bf2f((unsigned short)xv[j]);
    ss += s[j] * s[j];
  }
  #pragma unroll
  for (int m = 1; m <= 32; m <<= 1) ss += __shfl_xor(ss, m);
  if ((tid & 63) == 0) red[tid >> 6] = ss;
  __syncthreads();
  float ms = (red[0] + red[1] + red[2] + red[3]) * (1.f / DMODEL);
  float scl = rsqrtf(ms + EPS_C);
  floatx4 ov;
  #pragma unroll
  for (int j = 0; j < 4; j++) ov[j] = s[j] * scl * gv[j];
  *(floatx4*)(out + base + c) = ov;
}

// ---------------------------------------------------------------------------
// Workspace (bf16 elems), peak 58,720,256 = 112 MiB (proven OK round 4/5):
//   [0,        16.78M)  bf16 weights Wqkvb/Woutb/W1b/W2b (persistent)
//   [16.78M,   20.97M)  P1: xb -> attn-proj tmp
//   [20.97M,   25.17M)  x2
//   [25.17M,   37.75M)  q,k,v -> ys[4096,4096] after attn
//   [37.75M,   41.94M)  rope LUT (steps 0-1) -> o (steps 2-3)
//   [41.94M,   58.72M)  split-K f32 partials p0,p1 (step 6-7)
// ---------------------------------------------------------------------------
extern "C" void kernel_launch(void* const* d_in, const int* in_sizes, int n_in,
                              void* d_out, int out_size, void* d_ws, size_t ws_size,
                              hipStream_t stream) {
  (void)in_sizes; (void)n_in; (void)out_size; (void)ws_size;
  const float* x    = (const float*)d_in[0];
  const float* Wqkv = (const float*)d_in[1];
  const float* Wout = (const float*)d_in[2];
  const float* bout = (const float*)d_in[3];
  const float* W1   = (const float*)d_in[4];
  const float* W2   = (const float*)d_in[5];
  const float* g1   = (const float*)d_in[6];
  const float* g2   = (const float*)d_in[7];
  float* out = (float*)d_out;

  unsigned short* ws    = (unsigned short*)d_ws;
  unsigned short* Wqkvb = ws;
  unsigned short* Woutb = ws + 3145728;
  unsigned short* W1b   = ws + 4194304;
  unsigned short* W2b   = ws + 12582912;
  unsigned short* P1    = ws + 16777216;
  unsigned short* x2    = ws + 20971520;
  unsigned short* q     = ws + 25165824;
  unsigned short* k     = ws + 29360128;
  unsigned short* v     = ws + 33554432;
  unsigned short* o     = ws + 37748736;
  unsigned short* ys    = ws + 25165824;         // q/k/v dead after attn
  float* cosT = (float*)(ws + 37748736);         // LUT overlays o (dead then)
  float* sinT = cosT + 65536;
  float* p0   = (float*)(ws + 41943040);         // 4096*1024 f32
  float* p1   = (float*)(ws + 50331648);

  // 0. LUT + merged f32->bf16 conversion of all weights + x
  build_rope_lut<<<256, 256, 0, stream>>>(cosT, sinT);
  convert_all<<<10240, 256, 0, stream>>>(Wqkv, Wout, W1, W2, x, ws);
  // 1. qkv GEMM + fused RoPE/split -> q,k,v [B*H,T,64]
  gemm_qkv_rope<<<dim3(24, 32), 256, 0, stream>>>(P1, Wqkvb, cosT, sinT, q, k, v);
  // 2. MFMA banded attention -> o [B,T,1024]
  attn_mfma<<<32 * (T_SEQ / 64), 256, 0, stream>>>(q, k, v, o);
  // 3. a = o @ Wout^T + bout -> P1
  gemm_lds<64><<<dim3(16, 32), 256, 0, stream>>>(o, Woutb, P1, bout, 4096, 1024, 1024, 1024);
  // 4. x2 = rmsnorm(a + ALPHA*x, g1)
  rmsnorm_mid<<<4096, 256, 0, stream>>>(P1, x, g1, x2);
  // 5. W1 GEMM + fused SwiGLU -> ys [4096,4096]
  gemm_w1_swiglu<<<dim3(64, 32), 256, 0, stream>>>(x2, W1b, ys);
  // 6. y2 = ys @ W2^T (split-K=2) -> p0,p1 f32
  gemm_w2_splitk<<<dim3(16, 32, 2), 256, 0, stream>>>(ys, W2b, p0);
  // 7. out = rmsnorm(p0+p1 + ALPHA*x2, g2)
  rmsnorm_final_sk<<<4096, 256, 0, stream>>>(p0, p1, x2, g2, out);
}